// Round 8
// baseline (205.926 us; speedup 1.0000x reference)
//
#include <hip/hip_runtime.h>
#include <hip/hip_bf16.h>

typedef __bf16 bf16x8 __attribute__((ext_vector_type(8)));
typedef short short8 __attribute__((ext_vector_type(8)));
typedef float f32x4 __attribute__((ext_vector_type(4)));
typedef unsigned short ushort_t;

#define T_LEN 32768
#define B_SZ 4
#define NSLOW 2047
#define NSEQ (B_SZ * NSLOW)   // 8188
#define GH 64
#define G3 192
#define NL 4
#define HID 32
#define NCH 256               // fast-path chunks per batch (len 128)
#define L2E 1.44269504088896341f

// gru LDS: 64 KB history (16 seq x 32 t x 64 feat bf16, swizzled) +
// 13.5 KB f16 xacc ping-pong (2 pp x 3 gates x 16 seq x stride 72)
#define XB_STRIDE 72
#define XB_GATE  (16 * XB_STRIDE)       // 1152
#define XB_PP    (3 * XB_GATE)          // 3456
#define GRU_LDS  (65536 + 2 * XB_PP * 2)  // 79360 B

static __device__ __forceinline__ float bf2f(ushort_t u) {
    union { unsigned u; float f; } c; c.u = ((unsigned)u) << 16; return c.f;
}
static __device__ __forceinline__ ushort_t f2bf(float f) {
    union { float f; unsigned u; } c; c.f = f;
    unsigned r = (c.u + 0x7FFFu + ((c.u >> 16) & 1u)) >> 16;
    return (ushort_t)r;
}
static __device__ __forceinline__ unsigned pk2bf(float a, float b) {
    float2 f; f.x = a; f.y = b;
    __hip_bfloat162 h = __float22bfloat162_rn(f);   // v_cvt_pk_bf16_f32
    unsigned u;
    __builtin_memcpy(&u, &h, 4);
    return u;
}
static __device__ __forceinline__ ushort_t f16b(float f) {   // RTN f32->f16
    _Float16 h = (_Float16)f;
    ushort_t u; __builtin_memcpy(&u, &h, 2); return u;
}
static __device__ __forceinline__ float f16f(ushort_t u) {
    _Float16 h; __builtin_memcpy(&h, &u, 2); return (float)h;
}
static __device__ __forceinline__ float cvt(float v) { return v; }
static __device__ __forceinline__ float cvt(ushort_t v) { return bf2f(v); }
static __device__ __forceinline__ f32x4 mfma16(short8 a, short8 b, f32x4 c) {
    return __builtin_amdgcn_mfma_f32_16x16x32_bf16(
        __builtin_bit_cast(bf16x8, a), __builtin_bit_cast(bf16x8, b), c, 0, 0, 0);
}
// history layout: short off = ((t*8 + kb)*16 + (seq ^ (kb&7)))*8 + i
static __device__ __forceinline__ int xoff(int t, int kb, int seq) {
    return ((((t << 3) + kb) << 4) + (seq ^ (kb & 7))) << 3;
}

// dtype self-detection (block-uniform): bf16 N(0,1) data ~256/256 exponent
// fields in [80,141]; f32-read-as-ushort ~160/256.
static __device__ __forceinline__ bool detect_bf16(const void* xin) {
    const ushort_t* xb = (const ushort_t*)xin;
    int lane = threadIdx.x & 63;
    int cnt = 0;
#pragma unroll
    for (int i = 0; i < 4; ++i) {
        ushort_t u = xb[lane * 4 + i];
        int e = (u >> 7) & 0xFF;
        cnt += (e >= 80 && e <= 141) ? 1 : 0;
    }
#pragma unroll
    for (int d = 1; d < 64; d <<= 1) cnt += __shfl_xor(cnt, d, 64);
    return cnt >= 224;
}
static __device__ __forceinline__ float ldf(const void* p, bool isbf, int idx) {
    return isbf ? bf2f(((const ushort_t*)p)[idx]) : ((const float*)p)[idx];
}
// 8-elem MFMA fragment from either dtype, pre-scaled (once/layer: cheap)
static __device__ __forceinline__ short8 load_frag(const void* base, bool isbf,
                                                   int off, float s) {
    short8 o;
    if (isbf) {
        uint4 r = *(const uint4*)((const ushort_t*)base + off);
        unsigned aa[4] = {r.x, r.y, r.z, r.w};
#pragma unroll
        for (int i = 0; i < 4; ++i) {
            o[2 * i]     = (short)f2bf(bf2f((ushort_t)(aa[i] & 0xffffu)) * s);
            o[2 * i + 1] = (short)f2bf(bf2f((ushort_t)(aa[i] >> 16)) * s);
        }
    } else {
        const float4* p = (const float4*)((const float*)base + off);
        float4 a = p[0], b = p[1];
        o[0] = (short)f2bf(a.x * s); o[1] = (short)f2bf(a.y * s);
        o[2] = (short)f2bf(a.z * s); o[3] = (short)f2bf(a.w * s);
        o[4] = (short)f2bf(b.x * s); o[5] = (short)f2bf(b.y * s);
        o[6] = (short)f2bf(b.z * s); o[7] = (short)f2bf(b.w * s);
    }
    return o;
}

// ---- layer-0 fill (512 threads), dtype-monomorphic ----
template <typename T>
static __device__ __forceinline__ void fill_layer0(
    const T* __restrict__ xT, const T* __restrict__ fcwT,
    const T* __restrict__ fcbT, short8* __restrict__ Xs8, int tid, int n0)
{
    const int seq = tid & 15, kb = (tid >> 4) & 7;
    const int tb = tid >> 7;                 // 0..3
    int n = n0 + seq; if (n > NSEQ - 1) n = NSEQ - 1;
    int b = n / NSLOW, s = n - b * NSLOW;
    float wv[8], bv[8];
#pragma unroll
    for (int i = 0; i < 8; ++i) {
        wv[i] = cvt(fcwT[kb * 8 + i]);
        bv[i] = cvt(fcbT[kb * 8 + i]);
    }
    const T* xp = xT + b * T_LEN + s * 16;
#pragma unroll
    for (int ii = 0; ii < 8; ++ii) {
        int t = ii * 4 + tb;
        float xv = cvt(xp[t]);
        short8 v;
#pragma unroll
        for (int i = 0; i < 8; ++i) {
            float h = fmaf(xv, wv[i], bv[i]);
            v[i] = (short)f2bf(h > 0.f ? h : 0.f);
        }
        Xs8[xoff(t, kb, seq) >> 3] = v;
    }
}

// ---------------- K1: fused 4-layer GRU, producer/consumer waves ----------
// 512 thr: waves 0-3 (G) do h-MFMAs + gates + h-write for col-group jb;
// waves 4-7 (X) compute xacc(t+1)=bias+Wih*X(t+1) -> f16 xbuf ping-pong.
// One barrier/step; all same-interval LDS accesses are disjoint.
__global__ __launch_bounds__(512, 4) void gru_kernel(
    const void* __restrict__ xin, const void* __restrict__ fcw,
    const void* __restrict__ fcb, const void* __restrict__ wih,
    const void* __restrict__ whh, const void* __restrict__ bih,
    const void* __restrict__ bhh, const void* __restrict__ ofw,
    const void* __restrict__ ofb, float* __restrict__ Aslow,
    float* __restrict__ gslow)
{
    extern __shared__ short Xs[];
    short8* Xs8 = (short8*)Xs;
    ushort_t* xb = (ushort_t*)(Xs + 32768);
    const int tid = threadIdx.x;
    const int w = tid >> 6, lane = tid & 63;
    const int q = lane >> 4, m = lane & 15;
    const int p = w & 3, jb = p * 16;
    const bool isG = (w < 4);
    const int n0 = blockIdx.x * 16;

    const bool isbf = detect_bf16(xin);
    if (isbf)
        fill_layer0((const ushort_t*)xin, (const ushort_t*)fcw,
                    (const ushort_t*)fcb, Xs8, tid, n0);
    else
        fill_layer0((const float*)xin, (const float*)fcw,
                    (const float*)fcb, Xs8, tid, n0);

    const int col0 = jb + 4 * q;            // this lane's 4 gate-cols
    const int kbw = (col0 >> 3);
    const int wsub = (col0 & 7);
    const int kofs = q * 8;
    const int wbase0 = ((kbw << 4) + (m ^ (kbw & 7))) * 8 + wsub;
    const int xbo = m * XB_STRIDE + col0;   // + g*XB_GATE + pp*XB_PP
    const int iA = xoff(0, q, m) >> 3;      // history frag base, +128/t
    const int iB = xoff(0, 4 + q, m) >> 3;

    float hc[4];
#pragma unroll 1
    for (int l = 0; l < NL; ++l) {
        const int wl = l * G3 * GH;
        short8 f0, f1, f2, f3, f4, f5;
        f32x4 cR, cZ, cN;                   // X: bias inits; G: cN = bNH
        if (isG) {
            f0 = load_frag(whh, isbf, wl + (0 * 64 + jb + m) * 64 + kofs, -L2E);
            f1 = load_frag(whh, isbf, wl + (0 * 64 + jb + m) * 64 + 32 + kofs, -L2E);
            f2 = load_frag(whh, isbf, wl + (1 * 64 + jb + m) * 64 + kofs, -L2E);
            f3 = load_frag(whh, isbf, wl + (1 * 64 + jb + m) * 64 + 32 + kofs, -L2E);
            f4 = load_frag(whh, isbf, wl + (2 * 64 + jb + m) * 64 + kofs, 2.f * L2E);
            f5 = load_frag(whh, isbf, wl + (2 * 64 + jb + m) * 64 + 32 + kofs, 2.f * L2E);
#pragma unroll
            for (int i = 0; i < 4; ++i)
                cN[i] = 2.f * L2E * ldf(bhh, isbf, l * G3 + 128 + col0 + i);
        } else {
            f0 = load_frag(wih, isbf, wl + (0 * 64 + jb + m) * 64 + kofs, -L2E);
            f1 = load_frag(wih, isbf, wl + (0 * 64 + jb + m) * 64 + 32 + kofs, -L2E);
            f2 = load_frag(wih, isbf, wl + (1 * 64 + jb + m) * 64 + kofs, -L2E);
            f3 = load_frag(wih, isbf, wl + (1 * 64 + jb + m) * 64 + 32 + kofs, -L2E);
            f4 = load_frag(wih, isbf, wl + (2 * 64 + jb + m) * 64 + kofs, 2.f * L2E);
            f5 = load_frag(wih, isbf, wl + (2 * 64 + jb + m) * 64 + 32 + kofs, 2.f * L2E);
#pragma unroll
            for (int i = 0; i < 4; ++i) {
                int c = col0 + i;
                cR[i] = -L2E * (ldf(bih, isbf, l * G3 + c) + ldf(bhh, isbf, l * G3 + c));
                cZ[i] = -L2E * (ldf(bih, isbf, l * G3 + 64 + c) + ldf(bhh, isbf, l * G3 + 64 + c));
                cN[i] = 2.f * L2E * ldf(bih, isbf, l * G3 + 128 + c);
            }
        }
        hc[0] = hc[1] = hc[2] = hc[3] = 0.f;

        __syncthreads();                    // layer input fully written
        if (!isG) {                         // priming: xacc(0) -> xbuf[0]
            short8 x0 = Xs8[iA], x1 = Xs8[iB];
            f32x4 xR = cR, xZ = cZ, xN = cN;
            xR = mfma16(f0, x0, xR); xR = mfma16(f1, x1, xR);
            xZ = mfma16(f2, x0, xZ); xZ = mfma16(f3, x1, xZ);
            xN = mfma16(f4, x0, xN); xN = mfma16(f5, x1, xN);
            f32x4 acc3[3] = {xR, xZ, xN};
#pragma unroll
            for (int g = 0; g < 3; ++g) {
                uint2 v;
                v.x = f16b(acc3[g][0]) | ((unsigned)f16b(acc3[g][1]) << 16);
                v.y = f16b(acc3[g][2]) | ((unsigned)f16b(acc3[g][3]) << 16);
                *(uint2*)(xb + g * XB_GATE + xbo) = v;
            }
        }
        __syncthreads();

#pragma unroll 1
        for (int t = 0; t < 32; ++t) {
            if (isG) {
                int xo = (t & 1) * XB_PP + xbo;
                uint2 vR = *(const uint2*)(xb + xo);
                uint2 vZ = *(const uint2*)(xb + xo + XB_GATE);
                uint2 vN = *(const uint2*)(xb + xo + 2 * XB_GATE);
                f32x4 aR  = {f16f((ushort_t)vR.x), f16f((ushort_t)(vR.x >> 16)),
                             f16f((ushort_t)vR.y), f16f((ushort_t)(vR.y >> 16))};
                f32x4 aZ  = {f16f((ushort_t)vZ.x), f16f((ushort_t)(vZ.x >> 16)),
                             f16f((ushort_t)vZ.y), f16f((ushort_t)(vZ.y >> 16))};
                f32x4 aNX = {f16f((ushort_t)vN.x), f16f((ushort_t)(vN.x >> 16)),
                             f16f((ushort_t)vN.y), f16f((ushort_t)(vN.y >> 16))};
                f32x4 aNH = cN;
                if (t > 0) {
                    short8 bh0 = Xs8[iA + (t - 1) * 128];
                    short8 bh1 = Xs8[iB + (t - 1) * 128];
                    aR  = mfma16(f0, bh0, aR);  aR  = mfma16(f1, bh1, aR);
                    aZ  = mfma16(f2, bh0, aZ);  aZ  = mfma16(f3, bh1, aZ);
                    aNH = mfma16(f4, bh0, aNH); aNH = mfma16(f5, bh1, aNH);
                }
#pragma unroll
                for (int i = 0; i < 4; ++i) {
                    float r = __builtin_amdgcn_rcpf(1.f + __builtin_amdgcn_exp2f(aR[i]));
                    float z = __builtin_amdgcn_rcpf(1.f + __builtin_amdgcn_exp2f(aZ[i]));
                    float yp = fmaf(r, aNH[i], aNX[i]);
                    float nn = fmaf(-2.f,
                        __builtin_amdgcn_rcpf(1.f + __builtin_amdgcn_exp2f(yp)), 1.f);
                    hc[i] = fmaf(z, hc[i] - nn, nn);
                }
                *(uint2*)(Xs + wbase0 + t * 1024) =
                    make_uint2(pk2bf(hc[0], hc[1]), pk2bf(hc[2], hc[3]));
            } else if (t < 31) {            // xacc(t+1) -> xbuf[(t+1)&1]
                short8 x0 = Xs8[iA + (t + 1) * 128];
                short8 x1 = Xs8[iB + (t + 1) * 128];
                f32x4 xR = cR, xZ = cZ, xN = cN;
                xR = mfma16(f0, x0, xR); xR = mfma16(f1, x1, xR);
                xZ = mfma16(f2, x0, xZ); xZ = mfma16(f3, x1, xZ);
                xN = mfma16(f4, x0, xN); xN = mfma16(f5, x1, xN);
                f32x4 acc3[3] = {xR, xZ, xN};
                int xo = ((t + 1) & 1) * XB_PP + xbo;
#pragma unroll
                for (int g = 0; g < 3; ++g) {
                    uint2 v;
                    v.x = f16b(acc3[g][0]) | ((unsigned)f16b(acc3[g][1]) << 16);
                    v.y = f16b(acc3[g][2]) | ((unsigned)f16b(acc3[g][3]) << 16);
                    *(uint2*)(xb + xo + g * XB_GATE) = v;
                }
            }
            __syncthreads();
        }
    }

    // ---- epilogue (G-waves): eps = h_last @ out_fc_w^T + b ----
    if (isG) {
        short8 aL0 = Xs8[iA + 31 * 128];
        short8 aL1 = Xs8[iB + 31 * 128];
        float sc = (w < 2) ? -L2E : 1.f;
        short8 o0 = load_frag(ofw, isbf, (jb + m) * 64 + kofs, sc);
        short8 o1 = load_frag(ofw, isbf, (jb + m) * 64 + 32 + kofs, sc);
        f32x4 aE = {ldf(ofb, isbf, col0) * sc, ldf(ofb, isbf, col0 + 1) * sc,
                    ldf(ofb, isbf, col0 + 2) * sc, ldf(ofb, isbf, col0 + 3) * sc};
        aE = mfma16(o0, aL0, aE);
        aE = mfma16(o1, aL1, aE);
        int n = n0 + m;       // pad rows land in rows < 8192: harmless
        if (w < 2) {
            f32x4 v;
#pragma unroll
            for (int i = 0; i < 4; ++i)
                v[i] = __builtin_amdgcn_rcpf(1.f + __builtin_amdgcn_exp2f(aE[i]));
            *(f32x4*)(Aslow + n * HID + col0) = v;
        } else {
            *(f32x4*)(gslow + n * HID + (col0 - 32)) = aE;
        }
    }
}

// ---------------- K2: chunk summaries + BLOCK-LOCAL scan -> Hpre ----------
template <typename T>
static __device__ __forceinline__ void p1_body(
    const T* __restrict__ x, const float* __restrict__ Aslow,
    const float* __restrict__ gslow, const T* __restrict__ finw,
    const T* __restrict__ finb, float* __restrict__ Hpre,
    float* __restrict__ Pl, float* __restrict__ Sl, float* __restrict__ Hl,
    int tid, int bid)
{
    const int b = bid >> 3, h0 = (bid & 7) * 4;
#pragma unroll 1
    for (int p = 0; p < 4; ++p) {
        int idx = p * 256 + tid;
        int lh = idx & 3, c = idx >> 2;
        int h = h0 + lh;
        float fw = cvt(finw[h]), fb = cvt(finb[h]);
        float Pv = 1.f, Sv = 0.f;
        int t0 = c * 128;
#pragma unroll 1
        for (int seg = 0; seg < 8; ++seg) {
            int sidx = c * 8 + seg - 1;
            if (sidx < 0) sidx = 0;
            float A = Aslow[(b * NSLOW + sidx) * HID + h];
            float g = gslow[(b * NSLOW + sidx) * HID + h];
            float fwg = fw * g, fbg = fb * g;
            const T* px = x + b * T_LEN + t0 + seg * 16;
            float xs[16];
#pragma unroll
            for (int j = 0; j < 16; ++j) xs[j] = cvt(px[j]);
#pragma unroll
            for (int j = 0; j < 16; ++j)
                Sv = fmaf(A, Sv, fmaf(xs[j], fwg, fbg));
            float A2 = A * A, A4 = A2 * A2, A8 = A4 * A4;
            Pv *= A8 * A8;
        }
        Pl[c * 4 + lh] = Pv;
        Sl[c * 4 + lh] = Sv;
    }
    __syncthreads();
    if (tid < 4) {
        int lh = tid;
        float hr = 0.f;
#pragma unroll 4
        for (int c = 0; c < NCH; ++c) {
            float pv = Pl[c * 4 + lh], sv = Sl[c * 4 + lh];
            Hl[lh * NCH + c] = hr;
            hr = fmaf(pv, hr, sv);
        }
    }
    __syncthreads();
#pragma unroll 1
    for (int p = 0; p < 4; ++p) {
        int idx = p * 256 + tid;
        int lh = idx >> 8, c = idx & 255;
        Hpre[(b * HID + h0 + lh) * NCH + c] = Hl[lh * NCH + c];
    }
}

__global__ __launch_bounds__(256) void p1scan_kernel(
    const void* __restrict__ xin, const float* __restrict__ Aslow,
    const float* __restrict__ gslow, const void* __restrict__ finw,
    const void* __restrict__ finb, float* __restrict__ Hpre)
{
    __shared__ float Pl[NCH * 4], Sl[NCH * 4], Hl[4 * NCH];   // 12 KB
    const bool isbf = detect_bf16(xin);
    if (isbf)
        p1_body((const ushort_t*)xin, Aslow, gslow, (const ushort_t*)finw,
                (const ushort_t*)finb, Hpre, Pl, Sl, Hl, threadIdx.x, blockIdx.x);
    else
        p1_body((const float*)xin, Aslow, gslow, (const float*)finw,
                (const float*)finb, Hpre, Pl, Sl, Hl, threadIdx.x, blockIdx.x);
}

// ---------------- K3: recompute states + fused output dot ----------------
template <typename T>
static __device__ __forceinline__ void pass2_body(
    const T* __restrict__ x, const float* __restrict__ Aslow,
    const float* __restrict__ gslow, const float* __restrict__ Hpre,
    const T* __restrict__ finw, const T* __restrict__ finb,
    const T* __restrict__ fow, const T* __restrict__ fob,
    void* __restrict__ outv, int tid, int bid)
{
    int wv = bid * 4 + (tid >> 6);                  // 0..511
    int lane = tid & 63, half = lane >> 5, h = lane & 31;
    int pair = wv * 2 + half;                       // 0..1023 = b*NCH + c
    int b = pair >> 8, c = pair & 255;
    float hv = Hpre[(b * HID + h) * NCH + c];
    float fw = cvt(finw[h]), fb = cvt(finb[h]);
    float wo = cvt(fow[h]), ob = cvt(fob[0]);
    int t0 = c * 128;
#pragma unroll 1
    for (int blk = 0; blk < 4; ++blk) {
        float ykeep = 0.f;
        float A = 0.f, fwg = 0.f, fbg = 0.f;
#pragma unroll
        for (int tt = 0; tt < 32; ++tt) {
            int t = t0 + blk * 32 + tt;
            if ((tt & 15) == 0) {
                int sidx = (t >> 4) - 1;
                if (sidx < 0) sidx = 0;
                A = Aslow[(b * NSLOW + sidx) * HID + h];
                float g = gslow[(b * NSLOW + sidx) * HID + h];
                fwg = fw * g; fbg = fb * g;
            }
            float xv = cvt(x[b * T_LEN + t]);
            hv = fmaf(A, hv, fmaf(xv, fwg, fbg));
            float y = hv * wo;
            y += __shfl_xor(y, 1, 64);
            y += __shfl_xor(y, 2, 64);
            y += __shfl_xor(y, 4, 64);
            y += __shfl_xor(y, 8, 64);
            y += __shfl_xor(y, 16, 64);
            if (tt == h) ykeep = y + ob;
        }
        int oidx = b * T_LEN + t0 + blk * 32 + h;
        if (sizeof(T) == 2) ((ushort_t*)outv)[oidx] = f2bf(ykeep);
        else                ((float*)outv)[oidx] = ykeep;
    }
}

__global__ __launch_bounds__(256) void pass2_kernel(
    const void* __restrict__ xin, const float* __restrict__ Aslow,
    const float* __restrict__ gslow, const float* __restrict__ Hpre,
    const void* __restrict__ finw, const void* __restrict__ finb,
    const void* __restrict__ fow, const void* __restrict__ fob,
    void* __restrict__ outv)
{
    const bool isbf = detect_bf16(xin);
    if (isbf)
        pass2_body((const ushort_t*)xin, Aslow, gslow, Hpre,
                   (const ushort_t*)finw, (const ushort_t*)finb,
                   (const ushort_t*)fow, (const ushort_t*)fob,
                   outv, threadIdx.x, blockIdx.x);
    else
        pass2_body((const float*)xin, Aslow, gslow, Hpre,
                   (const float*)finw, (const float*)finb,
                   (const float*)fow, (const float*)fob,
                   outv, threadIdx.x, blockIdx.x);
}

extern "C" void kernel_launch(void* const* d_in, const int* in_sizes, int n_in,
                              void* d_out, int out_size, void* d_ws, size_t ws_size,
                              hipStream_t stream)
{
    const void* xin  = d_in[0];
    const void* fcw  = d_in[1];
    const void* fcb  = d_in[2];
    const void* wih  = d_in[3];
    const void* whh  = d_in[4];
    const void* bih  = d_in[5];
    const void* bhh  = d_in[6];
    const void* ofw  = d_in[7];
    const void* ofb  = d_in[8];
    const void* finw = d_in[9];
    const void* finb = d_in[10];
    const void* fow  = d_in[11];
    const void* fob  = d_in[12];

    float* Aslow = (float*)d_ws;               // 8192*32 f32 = 1 MB
    float* gslow = Aslow + 8192 * 32;          // 1 MB
    float* Hpre  = gslow + 8192 * 32;          // 4*32*NCH f32 = 128 KB

    hipFuncSetAttribute((const void*)gru_kernel,
                        hipFuncAttributeMaxDynamicSharedMemorySize, GRU_LDS);

    gru_kernel<<<dim3(512), dim3(512), GRU_LDS, stream>>>(
        xin, fcw, fcb, wih, whh, bih, bhh, ofw, ofb, Aslow, gslow);
    p1scan_kernel<<<dim3(32), dim3(256), 0, stream>>>(
        xin, Aslow, gslow, finw, finb, Hpre);
    pass2_kernel<<<dim3(128), dim3(256), 0, stream>>>(
        xin, Aslow, gslow, Hpre, finw, finb, fow, fob, d_out);
}